// Round 9
// baseline (185.342 us; speedup 1.0000x reference)
//
#include <hip/hip_runtime.h>

// Problem constants (B, C=1, H, W) from the reference.
#define H_ 1024
#define W_ 1024
#define B_ 16
#define TH 16                  // output rows per block (transposed ring state is small enough - r8 evidence)
#define STEPS (TH + 6)         // 22 input rows streamed (halo 3 each side)
#define GX (H_ / TH)           // 64 y-tiles per image
#define NBLK (GX * B_)         // 1024 blocks
#define NACC 13
#define TW 4                   // cols per thread
#define BT 256                 // threads per block; BT*TW == W_

// partials layout (SoA): partials[j * NBLK + bid]
//  j: 0=sum_pred, then k=3,5,7: {1,5,9}=sum_dil {2,6,10}=sum_p*dil
//                               {3,7,11}=sum_ero {4,8,12}=sum_p*ero

// Transposed elliptical decomposition (r8-verified, exact):
//   V3[x] = op(r[y-1..y+1][x]); V5[x] = op(V3[x], r[y-2][x], r[y+2][x]);
//   V7[x] = op(V5[x], r[y-3][x], r[y+3][x])
//   k3 = op(V3[x],  r0[x+/-1])
//   k5 = op(V5[x],  V3[x+/-1], r0[x+/-2])
//   k7 = op(V7[x],  V5[x+/-1], V5[x+/-2], r0[x+/-3])
// Live state = ONE raw 7-row ring shared by dil+ero (84 floats at TW=4) ->
// TH=16 unrolls without spill (r3's spill was the 148-float h-queue state).
// Geodesic (exclude-OOB) border == clamped-index border -> exact (r2/r5/r8).
__global__ __launch_bounds__(BT, 2) void k_partials(const float* __restrict__ pred,
                                                    const float* __restrict__ tch,
                                                    float* __restrict__ partials) {
  const int tid = threadIdx.x;
  // XCD swizzle (r6/r7: FETCH 90->67MB): same-XCD-consecutive blocks get
  // consecutive y-tiles of one image -> halo rows hit that XCD's L2.
  const int n     = blockIdx.y * gridDim.x + blockIdx.x;
  const int b     = n >> 6;                            // image (gridDim.x == 64)
  const int loc   = n & 63;
  const int ytile = (loc & 7) * 8 + (loc >> 3);        // bijective 0..63
  const int y0    = ytile * TH;
  const int x0    = tid * TW;
  const float* tb = tch  + (size_t)b * (H_ * W_);
  const float* pb = pred + (size_t)b * (H_ * W_);

  float acc[NACC];
#pragma unroll
  for (int j = 0; j < NACC; j++) acc[j] = 0.f;

  // raw ring: 7 rows x cols (x0-4 .. x0+7); i = col - (x0-4)
  float ring[7][12];

#pragma unroll
  for (int s = 0; s < STEPS; ++s) {
    // ---- load teacher row y0+s-3 (y-clamped, exact) into ring slot s%7
    {
      const int t    = y0 + s - 3;
      const int trow = t < 0 ? 0 : (t >= H_ ? H_ - 1 : t);
      const float* tr = tb + (size_t)trow * W_ + x0;
      const float4 v1 = *reinterpret_cast<const float4*>(tr);
      ring[s % 7][4] = v1.x; ring[s % 7][5] = v1.y; ring[s % 7][6] = v1.z; ring[s % 7][7] = v1.w;
      if (tid > 0) {
        const float4 vl = *reinterpret_cast<const float4*>(tr - 4);
        ring[s % 7][0] = vl.x; ring[s % 7][1] = vl.y; ring[s % 7][2] = vl.z; ring[s % 7][3] = vl.w;
      } else {                      // x-clamp left (exact)
        ring[s % 7][0] = ring[s % 7][1] = ring[s % 7][2] = ring[s % 7][3] = v1.x;
      }
      if (tid < BT - 1) {
        const float4 vr = *reinterpret_cast<const float4*>(tr + 4);
        ring[s % 7][8] = vr.x; ring[s % 7][9] = vr.y; ring[s % 7][10] = vr.z; ring[s % 7][11] = vr.w;
      } else {                      // x-clamp right (exact)
        ring[s % 7][8] = ring[s % 7][9] = ring[s % 7][10] = ring[s % 7][11] = v1.w;
      }
    }

    // ---- emit output row y = y0+s-6 (ring holds rows y-3..y+3)
    if (s >= 6) {
      // row y+d -> slot (s+4+d)%7:
      const float (&rm3)[12] = ring[(s + 1) % 7];
      const float (&rm2)[12] = ring[(s + 2) % 7];
      const float (&rm1)[12] = ring[(s + 3) % 7];
      const float (&rc )[12] = ring[(s + 4) % 7];
      const float (&rp1)[12] = ring[(s + 5) % 7];
      const float (&rp2)[12] = ring[(s + 6) % 7];
      const float (&rp3)[12] = ring[(s + 7) % 7];

      float V3M[12], V3N[12], V5M[12], V5N[12];
#pragma unroll
      for (int i = 2; i <= 9; ++i) {
        V3M[i] = fmaxf(fmaxf(rm1[i], rc[i]), rp1[i]);          // v_max3
        V3N[i] = fminf(fminf(rm1[i], rc[i]), rp1[i]);          // v_min3
        V5M[i] = fmaxf(fmaxf(V3M[i], rm2[i]), rp2[i]);
        V5N[i] = fminf(fminf(V3N[i], rm2[i]), rp2[i]);
      }
      const float* pr = pb + (size_t)(y0 + s - 6) * W_ + x0;
      const float4 p1 = *reinterpret_cast<const float4*>(pr);
      const float p[TW] = {p1.x, p1.y, p1.z, p1.w};
#pragma unroll
      for (int c = 0; c < TW; ++c) {
        const int i = c + 4;
        const float V7M = fmaxf(fmaxf(V5M[i], rm3[i]), rp3[i]);
        const float V7N = fminf(fminf(V5N[i], rm3[i]), rp3[i]);

        const float d3 = fmaxf(fmaxf(V3M[i], rc[i - 1]), rc[i + 1]);
        const float e3 = fminf(fminf(V3N[i], rc[i - 1]), rc[i + 1]);

        float d5 = fmaxf(fmaxf(V5M[i], V3M[i - 1]), V3M[i + 1]);
        d5 = fmaxf(fmaxf(d5, rc[i - 2]), rc[i + 2]);
        float e5 = fminf(fminf(V5N[i], V3N[i - 1]), V3N[i + 1]);
        e5 = fminf(fminf(e5, rc[i - 2]), rc[i + 2]);

        float d7 = fmaxf(fmaxf(V7M, V5M[i - 1]), V5M[i + 1]);
        d7 = fmaxf(fmaxf(d7, V5M[i - 2]), V5M[i + 2]);
        d7 = fmaxf(fmaxf(d7, rc[i - 3]), rc[i + 3]);
        float e7 = fminf(fminf(V7N, V5N[i - 1]), V5N[i + 1]);
        e7 = fminf(fminf(e7, V5N[i - 2]), V5N[i + 2]);
        e7 = fminf(fminf(e7, rc[i - 3]), rc[i + 3]);

        acc[0]  += p[c];
        acc[1]  += d3;  acc[2]  = fmaf(p[c], d3, acc[2]);
        acc[3]  += e3;  acc[4]  = fmaf(p[c], e3, acc[4]);
        acc[5]  += d5;  acc[6]  = fmaf(p[c], d5, acc[6]);
        acc[7]  += e5;  acc[8]  = fmaf(p[c], e5, acc[8]);
        acc[9]  += d7;  acc[10] = fmaf(p[c], d7, acc[10]);
        acc[11] += e7;  acc[12] = fmaf(p[c], e7, acc[12]);
      }
    }
  }

  // wave (64-lane) shuffle reduction, then cross-wave via LDS
#pragma unroll
  for (int j = 0; j < NACC; j++) {
    float v = acc[j];
#pragma unroll
    for (int off = 32; off > 0; off >>= 1) v += __shfl_down(v, off, 64);
    acc[j] = v;
  }
  __shared__ float red[4][NACC];
  const int lane = tid & 63, wv = tid >> 6;
  if (lane == 0) {
#pragma unroll
    for (int j = 0; j < NACC; j++) red[wv][j] = acc[j];
  }
  __syncthreads();
  if (tid == 0) {
#pragma unroll
    for (int j = 0; j < NACC; j++)
      partials[j * NBLK + n] = red[0][j] + red[1][j] + red[2][j] + red[3][j];
  }
}

__global__ __launch_bounds__(256) void k_final(const float* __restrict__ partials,
                                               float* __restrict__ out) {
  const int tid = threadIdx.x;
  double acc[NACC];
#pragma unroll
  for (int j = 0; j < NACC; j++) acc[j] = 0.0;
#pragma unroll
  for (int k = 0; k < NBLK / 256; k++) {
#pragma unroll
    for (int j = 0; j < NACC; j++)
      acc[j] += (double)partials[j * NBLK + tid + k * 256];   // coalesced, independent
  }
#pragma unroll
  for (int j = 0; j < NACC; j++) {
#pragma unroll
    for (int off = 32; off > 0; off >>= 1) acc[j] += __shfl_down(acc[j], off, 64);
  }
  __shared__ double red[4][NACC];
  const int lane = tid & 63, wv = tid >> 6;
  if (lane == 0) {
#pragma unroll
    for (int j = 0; j < NACC; j++) red[wv][j] = acc[j];
  }
  __syncthreads();
  if (tid == 0) {
    double t_[NACC];
#pragma unroll
    for (int j = 0; j < NACC; j++) t_[j] = red[0][j] + red[1][j] + red[2][j] + red[3][j];
    const double Sp = t_[0];
    double total = 0.0;
#pragma unroll
    for (int k = 0; k < 3; k++) {
      const double Sd = t_[1 + 4 * k], Id = t_[2 + 4 * k];
      const double Se = t_[3 + 4 * k], Ie = t_[4 + 4 * k];
      double cd = Sp + Sd; if (cd < 1e-7) cd = 1e-7;
      double ce = Sp + Se; if (ce < 1e-7) ce = 1e-7;
      total += (1.0 - 2.0 * Id / cd) * (Sd > 0.0 ? 1.0 : 0.0);
      total += (1.0 - 2.0 * Ie / ce) * (Se > 0.0 ? 1.0 : 0.0);
    }
    out[0] = (float)(total / 3.0);
  }
}

extern "C" void kernel_launch(void* const* d_in, const int* in_sizes, int n_in,
                              void* d_out, int out_size, void* d_ws, size_t ws_size,
                              hipStream_t stream) {
  const float* pred = (const float*)d_in[0];  // pred_student_prob
  const float* tch  = (const float*)d_in[1];  // teacher_prob
  float* partials = (float*)d_ws;             // NACC * NBLK floats; fully written each launch

  k_partials<<<dim3(GX, B_), BT, 0, stream>>>(pred, tch, partials);
  k_final<<<1, 256, 0, stream>>>(partials, (float*)d_out);
}

// Round 10
// 157.593 us; speedup vs baseline: 1.1761x; 1.1761x over previous
//
#include <hip/hip_runtime.h>

// Problem constants (B, C=1, H, W) from the reference.
#define H_ 1024
#define W_ 1024
#define B_ 16
#define TH 4                   // output rows per block: small TH is cheap in the transposed form
                               // (warm-up steps are loads-only) and doubles wave count vs TH=8
#define STEPS (TH + 6)         // 10 input rows streamed (halo 3 each side)
#define GX (H_ / TH)           // 256 y-tiles per image
#define NBLK (GX * B_)         // 4096 blocks -> 16K waves (2x r2) for latency overlap
#define NACC 13
#define TW 4                   // cols per thread
#define BT 256                 // threads per block; BT*TW == W_

// partials layout (SoA): partials[j * NBLK + bid]
//  j: 0=sum_pred, then k=3,5,7: {1,5,9}=sum_dil {2,6,10}=sum_p*dil
//                               {3,7,11}=sum_ero {4,8,12}=sum_p*ero

// Transposed elliptical decomposition (r8/r9-verified, exact):
//   V3[x] = op(r[y-1..y+1][x]); V5[x] = op(V3[x], r[y-2][x], r[y+2][x]);
//   V7[x] = op(V5[x], r[y-3][x], r[y+3][x])
//   k3 = op(V3[x],  r0[x+/-1])
//   k5 = op(V5[x],  V3[x+/-1], r0[x+/-2])
//   k7 = op(V7[x],  V5[x+/-1], V5[x+/-2], r0[x+/-3])
// Emit is split MAX-phase then MIN-phase so only ONE op's V3/V5 transients
// (16 floats) are live at a time -> state fits the 128-VGPR cap without the
// r9 spill (r9 kept both: ~32 transients + ring -> spilled at cap 128).
// Live state: raw 7-row ring shared by dil+ero (70 floats after end-col DCE).
// Geodesic (exclude-OOB) border == clamped-index border -> exact (r2/r5/r8/r9).
__global__ __launch_bounds__(BT, 2) void k_partials(const float* __restrict__ pred,
                                                    const float* __restrict__ tch,
                                                    float* __restrict__ partials) {
  const int tid = threadIdx.x;
  // XCD swizzle (r6/r7: FETCH 90->67MB): same-XCD-consecutive blocks get
  // consecutive y-tiles of one image -> halo rows hit that XCD's L2.
  const int n     = blockIdx.y * gridDim.x + blockIdx.x;
  const int b     = n >> 8;                            // image (gridDim.x == 256)
  const int loc   = n & 255;
  const int ytile = (loc & 7) * 32 + (loc >> 3);       // bijective 0..255
  const int y0    = ytile * TH;
  const int x0    = tid * TW;
  const float* tb = tch  + (size_t)b * (H_ * W_);
  const float* pb = pred + (size_t)b * (H_ * W_);

  float acc[NACC];
#pragma unroll
  for (int j = 0; j < NACC; j++) acc[j] = 0.f;

  // raw ring: 7 rows x cols (x0-4 .. x0+7); i = col - (x0-4). Cols 0,11 DCE.
  float ring[7][12];

#pragma unroll
  for (int s = 0; s < STEPS; ++s) {
    // ---- load teacher row y0+s-3 (y-clamped, exact) into ring slot s%7
    {
      const int t    = y0 + s - 3;
      const int trow = t < 0 ? 0 : (t >= H_ ? H_ - 1 : t);
      const float* tr = tb + (size_t)trow * W_ + x0;
      const float4 v1 = *reinterpret_cast<const float4*>(tr);
      ring[s % 7][4] = v1.x; ring[s % 7][5] = v1.y; ring[s % 7][6] = v1.z; ring[s % 7][7] = v1.w;
      if (tid > 0) {
        const float4 vl = *reinterpret_cast<const float4*>(tr - 4);
        ring[s % 7][0] = vl.x; ring[s % 7][1] = vl.y; ring[s % 7][2] = vl.z; ring[s % 7][3] = vl.w;
      } else {                      // x-clamp left (exact)
        ring[s % 7][0] = ring[s % 7][1] = ring[s % 7][2] = ring[s % 7][3] = v1.x;
      }
      if (tid < BT - 1) {
        const float4 vr = *reinterpret_cast<const float4*>(tr + 4);
        ring[s % 7][8] = vr.x; ring[s % 7][9] = vr.y; ring[s % 7][10] = vr.z; ring[s % 7][11] = vr.w;
      } else {                      // x-clamp right (exact)
        ring[s % 7][8] = ring[s % 7][9] = ring[s % 7][10] = ring[s % 7][11] = v1.w;
      }
    }

    // ---- emit output row y = y0+s-6 (ring holds rows y-3..y+3)
    if (s >= 6) {
      // row y+d -> ring slot (s+4+d)%7
      const float (&rm3)[12] = ring[(s + 1) % 7];
      const float (&rm2)[12] = ring[(s + 2) % 7];
      const float (&rm1)[12] = ring[(s + 3) % 7];
      const float (&rc )[12] = ring[(s + 4) % 7];
      const float (&rp1)[12] = ring[(s + 5) % 7];
      const float (&rp2)[12] = ring[(s + 6) % 7];
      const float (&rp3)[12] = ring[s % 7];

      const float* pr = pb + (size_t)(y0 + s - 6) * W_ + x0;
      const float4 p1 = *reinterpret_cast<const float4*>(pr);
      const float p[TW] = {p1.x, p1.y, p1.z, p1.w};

      // ===== MAX (dilation) phase =====
      {
        float V3[12], V5[12];
#pragma unroll
        for (int i = 2; i <= 9; ++i) {
          V3[i] = fmaxf(fmaxf(rm1[i], rc[i]), rp1[i]);          // v_max3
          V5[i] = fmaxf(fmaxf(V3[i], rm2[i]), rp2[i]);
        }
#pragma unroll
        for (int c = 0; c < TW; ++c) {
          const int i = c + 4;
          const float V7 = fmaxf(fmaxf(V5[i], rm3[i]), rp3[i]);
          const float d3 = fmaxf(fmaxf(V3[i], rc[i - 1]), rc[i + 1]);
          float d5 = fmaxf(fmaxf(V5[i], V3[i - 1]), V3[i + 1]);
          d5 = fmaxf(fmaxf(d5, rc[i - 2]), rc[i + 2]);
          float d7 = fmaxf(fmaxf(V7, V5[i - 1]), V5[i + 1]);
          d7 = fmaxf(fmaxf(d7, V5[i - 2]), V5[i + 2]);
          d7 = fmaxf(fmaxf(d7, rc[i - 3]), rc[i + 3]);
          acc[0]  += p[c];
          acc[1]  += d3;  acc[2]  = fmaf(p[c], d3, acc[2]);
          acc[5]  += d5;  acc[6]  = fmaf(p[c], d5, acc[6]);
          acc[9]  += d7;  acc[10] = fmaf(p[c], d7, acc[10]);
        }
      }
      // ===== MIN (erosion) phase =====
      {
        float V3[12], V5[12];
#pragma unroll
        for (int i = 2; i <= 9; ++i) {
          V3[i] = fminf(fminf(rm1[i], rc[i]), rp1[i]);          // v_min3
          V5[i] = fminf(fminf(V3[i], rm2[i]), rp2[i]);
        }
#pragma unroll
        for (int c = 0; c < TW; ++c) {
          const int i = c + 4;
          const float V7 = fminf(fminf(V5[i], rm3[i]), rp3[i]);
          const float e3 = fminf(fminf(V3[i], rc[i - 1]), rc[i + 1]);
          float e5 = fminf(fminf(V5[i], V3[i - 1]), V3[i + 1]);
          e5 = fminf(fminf(e5, rc[i - 2]), rc[i + 2]);
          float e7 = fminf(fminf(V7, V5[i - 1]), V5[i + 1]);
          e7 = fminf(fminf(e7, V5[i - 2]), V5[i + 2]);
          e7 = fminf(fminf(e7, rc[i - 3]), rc[i + 3]);
          acc[3]  += e3;  acc[4]  = fmaf(p[c], e3, acc[4]);
          acc[7]  += e5;  acc[8]  = fmaf(p[c], e5, acc[8]);
          acc[11] += e7;  acc[12] = fmaf(p[c], e7, acc[12]);
        }
      }
    }
  }

  // wave (64-lane) shuffle reduction, then cross-wave via LDS
#pragma unroll
  for (int j = 0; j < NACC; j++) {
    float v = acc[j];
#pragma unroll
    for (int off = 32; off > 0; off >>= 1) v += __shfl_down(v, off, 64);
    acc[j] = v;
  }
  __shared__ float red[4][NACC];
  const int lane = tid & 63, wv = tid >> 6;
  if (lane == 0) {
#pragma unroll
    for (int j = 0; j < NACC; j++) red[wv][j] = acc[j];
  }
  __syncthreads();
  if (tid == 0) {
#pragma unroll
    for (int j = 0; j < NACC; j++)
      partials[j * NBLK + n] = red[0][j] + red[1][j] + red[2][j] + red[3][j];
  }
}

__global__ __launch_bounds__(256) void k_final(const float* __restrict__ partials,
                                               float* __restrict__ out) {
  const int tid = threadIdx.x;
  double acc[NACC];
#pragma unroll
  for (int j = 0; j < NACC; j++) acc[j] = 0.0;
#pragma unroll
  for (int k = 0; k < NBLK / 256; k++) {
#pragma unroll
    for (int j = 0; j < NACC; j++)
      acc[j] += (double)partials[j * NBLK + tid + k * 256];   // coalesced, independent
  }
#pragma unroll
  for (int j = 0; j < NACC; j++) {
#pragma unroll
    for (int off = 32; off > 0; off >>= 1) acc[j] += __shfl_down(acc[j], off, 64);
  }
  __shared__ double red[4][NACC];
  const int lane = tid & 63, wv = tid >> 6;
  if (lane == 0) {
#pragma unroll
    for (int j = 0; j < NACC; j++) red[wv][j] = acc[j];
  }
  __syncthreads();
  if (tid == 0) {
    double t_[NACC];
#pragma unroll
    for (int j = 0; j < NACC; j++) t_[j] = red[0][j] + red[1][j] + red[2][j] + red[3][j];
    const double Sp = t_[0];
    double total = 0.0;
#pragma unroll
    for (int k = 0; k < 3; k++) {
      const double Sd = t_[1 + 4 * k], Id = t_[2 + 4 * k];
      const double Se = t_[3 + 4 * k], Ie = t_[4 + 4 * k];
      double cd = Sp + Sd; if (cd < 1e-7) cd = 1e-7;
      double ce = Sp + Se; if (ce < 1e-7) ce = 1e-7;
      total += (1.0 - 2.0 * Id / cd) * (Sd > 0.0 ? 1.0 : 0.0);
      total += (1.0 - 2.0 * Ie / ce) * (Se > 0.0 ? 1.0 : 0.0);
    }
    out[0] = (float)(total / 3.0);
  }
}

extern "C" void kernel_launch(void* const* d_in, const int* in_sizes, int n_in,
                              void* d_out, int out_size, void* d_ws, size_t ws_size,
                              hipStream_t stream) {
  const float* pred = (const float*)d_in[0];  // pred_student_prob
  const float* tch  = (const float*)d_in[1];  // teacher_prob
  float* partials = (float*)d_ws;             // NACC * NBLK floats; fully written each launch

  k_partials<<<dim3(GX, B_), BT, 0, stream>>>(pred, tch, partials);
  k_final<<<1, 256, 0, stream>>>(partials, (float*)d_out);
}

// Round 11
// 155.957 us; speedup vs baseline: 1.1884x; 1.0105x over previous
//
#include <hip/hip_runtime.h>

// Problem constants (B, C=1, H, W) from the reference.
#define H_ 1024
#define W_ 1024
#define B_ 16
#define TH 4                   // output rows per block (warm-up is loads-only in transposed form)
#define STEPS (TH + 6)         // 10 input rows streamed (halo 3 each side)
#define GX (H_ / TH)           // 256 y-tiles per image
#define NBLK (GX * B_)         // 4096 blocks
#define NACC 13
#define TW 4                   // cols per thread
#define BT 256                 // threads per block; BT*TW == W_

// d_ws layout: partials[NACC * NBLK] (SoA: partials[j*NBLK + bid]) then red13[NACC].
//  j: 0=sum_pred, then k=3,5,7: {1,5,9}=sum_dil {2,6,10}=sum_p*dil
//                               {3,7,11}=sum_ero {4,8,12}=sum_p*ero

// Transposed elliptical decomposition (r8/r9/r10-verified, exact):
//   V3 = op over rows y+/-1; V5 = op(V3, rows y+/-2); V7 = op(V5, rows y+/-3)
//   k3 = op(V3[x], rc[x+/-1]); k5 = op(V5[x], V3[x+/-1], rc[x+/-2]);
//   k7 = op(V7[x], V5[x+/-1], V5[x+/-2], rc[x+/-3])
// NEW vs r10: each thread loads ONLY its own float4 per teacher row; halo
// cols (x0-3..x0-1, x0+4..x0+6) are produced by __shfl of the row once it is
// register-resident (next step), with 1-lane predicated loads at wave edges.
// The +/-3-row terms (rm3/rp3) need own cols only (ellipse width 0 at dy=+/-3),
// so the same-step load feeds just the 2 final max3/min3 ops -> chain hidden.
// Ring rows store 10 cols: i=0..9 <-> col x0-3+i (own = i 3..6).
// Geodesic border == clamped-index border -> exact (verified r2..r10).
__global__ __launch_bounds__(BT, 4) void k_partials(const float* __restrict__ pred,
                                                    const float* __restrict__ tch,
                                                    float* __restrict__ partials) {
  const int tid  = threadIdx.x;
  const int lane = tid & 63;
  // XCD swizzle (r6/r7: FETCH 90->67MB)
  const int n     = blockIdx.y * gridDim.x + blockIdx.x;
  const int b     = n >> 8;                            // image (gridDim.x == 256)
  const int loc   = n & 255;
  const int ytile = (loc & 7) * 32 + (loc >> 3);       // bijective 0..255
  const int y0    = ytile * TH;
  const int x0    = tid * TW;
  const float* tb = tch  + (size_t)b * (H_ * W_);
  const float* pb = pred + (size_t)b * (H_ * W_);

  float acc[NACC];
#pragma unroll
  for (int j = 0; j < NACC; j++) acc[j] = 0.f;

  float ring[7][10];          // [slot][i], col = x0-3+i
  const float* trp = nullptr; // previous step's (clamped) teacher row pointer
  float4 pv, pvn;

#pragma unroll
  for (int s = 0; s < STEPS; ++s) {
    // ---- resolve halo of the row loaded at step s-1 (register shuffles)
    if (s >= 1) {
      const int sl = (s - 1) % 7;
      const float a3 = ring[sl][3], a4 = ring[sl][4], a5 = ring[sl][5], a6 = ring[sl][6];
      ring[sl][0] = __shfl_up(a4, 1, 64);    // col x0-3 = prev lane's x0'+1
      ring[sl][1] = __shfl_up(a5, 1, 64);    // col x0-2
      ring[sl][2] = __shfl_up(a6, 1, 64);    // col x0-1
      ring[sl][7] = __shfl_down(a3, 1, 64);  // col x0+4 = next lane's x0''
      ring[sl][8] = __shfl_down(a4, 1, 64);  // col x0+5
      ring[sl][9] = __shfl_down(a5, 1, 64);  // col x0+6
      if (lane == 0) {                       // wave-left edge: true neighbor is prev wave
        if (tid > 0) {
          const float4 el = *reinterpret_cast<const float4*>(trp + x0 - 4);
          ring[sl][0] = el.y; ring[sl][1] = el.z; ring[sl][2] = el.w;
        } else {                             // image edge: x-clamp (exact)
          ring[sl][0] = ring[sl][1] = ring[sl][2] = a3;
        }
      }
      if (lane == 63) {                      // wave-right edge
        if (tid < BT - 1) {
          const float4 er = *reinterpret_cast<const float4*>(trp + x0 + 4);
          ring[sl][7] = er.x; ring[sl][8] = er.y; ring[sl][9] = er.z;
        } else {                             // image edge: x-clamp (exact)
          ring[sl][7] = ring[sl][8] = ring[sl][9] = a6;
        }
      }
    }

    // ---- load own float4 of teacher row y0+s-3 (y-clamped, exact)
    {
      const int t    = y0 + s - 3;
      const int trow = t < 0 ? 0 : (t >= H_ ? H_ - 1 : t);
      const float* tr = tb + (size_t)trow * W_;
      const float4 v  = *reinterpret_cast<const float4*>(tr + x0);
      const int sl = s % 7;
      ring[sl][3] = v.x; ring[sl][4] = v.y; ring[sl][5] = v.z; ring[sl][6] = v.w;
      trp = tr;
    }

    // ---- pred prefetch chain (emit at s uses row y0+s-6)
    if (s == 5) pvn = *reinterpret_cast<const float4*>(pb + (size_t)y0 * W_ + x0);

    // ---- emit output row y = y0+s-6 (rows y-3..y+2 fully resolved; y+3 own-only)
    if (s >= 6) {
      pv = pvn;
      if (s < STEPS - 1)
        pvn = *reinterpret_cast<const float4*>(pb + (size_t)(y0 + s - 5) * W_ + x0);
      // row y+d -> slot (s-3+d)%7
      const float (&rm3)[10] = ring[(s - 6) % 7];
      const float (&rm2)[10] = ring[(s - 5) % 7];
      const float (&rm1)[10] = ring[(s - 4) % 7];
      const float (&rc )[10] = ring[(s - 3) % 7];
      const float (&rp1)[10] = ring[(s - 2) % 7];
      const float (&rp2)[10] = ring[(s - 1) % 7];
      const float (&rp3)[10] = ring[s % 7];          // own cols i=3..6 only
      const float p[TW] = {pv.x, pv.y, pv.z, pv.w};

      // ===== MAX (dilation) phase =====
      {
        float V3[10], V5[10];
#pragma unroll
        for (int i = 1; i <= 8; ++i) {
          V3[i] = fmaxf(fmaxf(rm1[i], rc[i]), rp1[i]);          // v_max3
          V5[i] = fmaxf(fmaxf(V3[i], rm2[i]), rp2[i]);
        }
#pragma unroll
        for (int c = 0; c < TW; ++c) {
          const int i = c + 3;
          const float V7 = fmaxf(fmaxf(V5[i], rm3[i]), rp3[i]); // rp3: same-step own col
          const float d3 = fmaxf(fmaxf(V3[i], rc[i - 1]), rc[i + 1]);
          float d5 = fmaxf(fmaxf(V5[i], V3[i - 1]), V3[i + 1]);
          d5 = fmaxf(fmaxf(d5, rc[i - 2]), rc[i + 2]);
          float d7 = fmaxf(fmaxf(V7, V5[i - 1]), V5[i + 1]);
          d7 = fmaxf(fmaxf(d7, V5[i - 2]), V5[i + 2]);
          d7 = fmaxf(fmaxf(d7, rc[i - 3]), rc[i + 3]);
          acc[0]  += p[c];
          acc[1]  += d3;  acc[2]  = fmaf(p[c], d3, acc[2]);
          acc[5]  += d5;  acc[6]  = fmaf(p[c], d5, acc[6]);
          acc[9]  += d7;  acc[10] = fmaf(p[c], d7, acc[10]);
        }
      }
      // ===== MIN (erosion) phase =====
      {
        float V3[10], V5[10];
#pragma unroll
        for (int i = 1; i <= 8; ++i) {
          V3[i] = fminf(fminf(rm1[i], rc[i]), rp1[i]);          // v_min3
          V5[i] = fminf(fminf(V3[i], rm2[i]), rp2[i]);
        }
#pragma unroll
        for (int c = 0; c < TW; ++c) {
          const int i = c + 3;
          const float V7 = fminf(fminf(V5[i], rm3[i]), rp3[i]);
          const float e3 = fminf(fminf(V3[i], rc[i - 1]), rc[i + 1]);
          float e5 = fminf(fminf(V5[i], V3[i - 1]), V3[i + 1]);
          e5 = fminf(fminf(e5, rc[i - 2]), rc[i + 2]);
          float e7 = fminf(fminf(V7, V5[i - 1]), V5[i + 1]);
          e7 = fminf(fminf(e7, V5[i - 2]), V5[i + 2]);
          e7 = fminf(fminf(e7, rc[i - 3]), rc[i + 3]);
          acc[3]  += e3;  acc[4]  = fmaf(p[c], e3, acc[4]);
          acc[7]  += e5;  acc[8]  = fmaf(p[c], e5, acc[8]);
          acc[11] += e7;  acc[12] = fmaf(p[c], e7, acc[12]);
        }
      }
    }
  }

  // wave (64-lane) shuffle reduction, then cross-wave via LDS
#pragma unroll
  for (int j = 0; j < NACC; j++) {
    float v = acc[j];
#pragma unroll
    for (int off = 32; off > 0; off >>= 1) v += __shfl_down(v, off, 64);
    acc[j] = v;
  }
  __shared__ float red[4][NACC];
  const int wv = tid >> 6;
  if (lane == 0) {
#pragma unroll
    for (int j = 0; j < NACC; j++) red[wv][j] = acc[j];
  }
  __syncthreads();
  if (tid == 0) {
#pragma unroll
    for (int j = 0; j < NACC; j++)
      partials[j * NBLK + n] = red[0][j] + red[1][j] + red[2][j] + red[3][j];
  }
}

// Stage-1 reduction: block j sums partials[j*NBLK .. +NBLK) -> red13[j].
__global__ __launch_bounds__(256) void k_red(const float* __restrict__ partials,
                                             float* __restrict__ red13) {
  const int j   = blockIdx.x;
  const int tid = threadIdx.x;
  double a = 0.0;
#pragma unroll
  for (int k = 0; k < NBLK / 256; k++)
    a += (double)partials[j * NBLK + tid + k * 256];   // coalesced, independent
#pragma unroll
  for (int off = 32; off > 0; off >>= 1) a += __shfl_down(a, off, 64);
  __shared__ double red[4];
  const int lane = tid & 63, wv = tid >> 6;
  if (lane == 0) red[wv] = a;
  __syncthreads();
  if (tid == 0) red13[j] = (float)0, red13[j] = (float)(red[0] + red[1] + red[2] + red[3]);
}

__global__ void k_final(const float* __restrict__ red13, float* __restrict__ out) {
  if (threadIdx.x == 0) {
    double t_[NACC];
#pragma unroll
    for (int j = 0; j < NACC; j++) t_[j] = (double)red13[j];
    const double Sp = t_[0];
    double total = 0.0;
#pragma unroll
    for (int k = 0; k < 3; k++) {
      const double Sd = t_[1 + 4 * k], Id = t_[2 + 4 * k];
      const double Se = t_[3 + 4 * k], Ie = t_[4 + 4 * k];
      double cd = Sp + Sd; if (cd < 1e-7) cd = 1e-7;
      double ce = Sp + Se; if (ce < 1e-7) ce = 1e-7;
      total += (1.0 - 2.0 * Id / cd) * (Sd > 0.0 ? 1.0 : 0.0);
      total += (1.0 - 2.0 * Ie / ce) * (Se > 0.0 ? 1.0 : 0.0);
    }
    out[0] = (float)(total / 3.0);
  }
}

extern "C" void kernel_launch(void* const* d_in, const int* in_sizes, int n_in,
                              void* d_out, int out_size, void* d_ws, size_t ws_size,
                              hipStream_t stream) {
  const float* pred = (const float*)d_in[0];  // pred_student_prob
  const float* tch  = (const float*)d_in[1];  // teacher_prob
  float* partials = (float*)d_ws;                       // NACC*NBLK floats
  float* red13    = (float*)d_ws + NACC * NBLK;         // NACC floats

  k_partials<<<dim3(GX, B_), BT, 0, stream>>>(pred, tch, partials);
  k_red<<<NACC, 256, 0, stream>>>(partials, red13);
  k_final<<<1, 64, 0, stream>>>(red13, (float*)d_out);
}

// Round 12
// 147.922 us; speedup vs baseline: 1.2530x; 1.0543x over previous
//
#include <hip/hip_runtime.h>

// Problem constants (B, C=1, H, W) from the reference.
#define H_ 1024
#define W_ 1024
#define B_ 16
#define TH 4                   // output rows per block
#define STEPS (TH + 6)         // 10 teacher rows per block (halo 3 each side)
#define GX (H_ / TH)           // 256 y-tiles per image
#define NBLK (GX * B_)         // 4096 blocks
#define NACC 13
#define TW 4                   // cols per thread
#define BT 256                 // threads per block; BT*TW == W_ (block edges == image edges)

// d_ws layout: partials[NACC*NBLK] (SoA) then red13[NACC].
//  j: 0=sum_pred, then k=3,5,7: {1,5,9}=sum_dil {2,6,10}=sum_p*dil
//                               {3,7,11}=sum_ero {4,8,12}=sum_p*ero

// Transposed elliptical decomposition (verified r8-r11, exact):
//   V3 = op rows y+/-1; V5 = op(V3, rows y+/-2); V7 = op(V5, rows y+/-3)
//   k3 = op(V3[x], rc[x+/-1]); k5 = op(V5[x], V3[x+/-1], rc[x+/-2]);
//   k7 = op(V7[x], V5[x+/-1], V5[x+/-2], rc[x+/-3])
// NEW vs r11 (52.7us, BW-limited at 1.35TB/s by ~1 outstanding load/wave):
// ALL 10 teacher loads (own float4 only) issued up front -> 160B/lane in
// flight (Little's law: ~10x MLP). Wave-boundary halo cols come from a tiny
// LDS edge exchange (lane0/63 publish their own float4 per row); block
// spans the full image row so block edges are image edges -> pure x-clamp.
// One barrier; compute (phase-split max/min) runs load-free.
// Geodesic border == clamped-index border -> exact (verified r2..r11).
__global__ __launch_bounds__(BT, 4) void k_partials(const float* __restrict__ pred,
                                                    const float* __restrict__ tch,
                                                    float* __restrict__ partials) {
  const int tid  = threadIdx.x;
  const int lane = tid & 63;
  const int wv   = tid >> 6;
  // XCD swizzle (r6/r7: FETCH 90->67MB)
  const int n     = blockIdx.y * gridDim.x + blockIdx.x;
  const int b     = n >> 8;                            // image (gridDim.x == 256)
  const int loc   = n & 255;
  const int ytile = (loc & 7) * 32 + (loc >> 3);       // bijective 0..255
  const int y0    = ytile * TH;
  const int x0    = tid * TW;
  const float* tb = tch  + (size_t)b * (H_ * W_);
  const float* pb = pred + (size_t)b * (H_ * W_);

  // edge exchange: eL[w][s] = wave w lane0's own float4, eR[w][s] = lane63's
  __shared__ float eL[4][STEPS][4], eR[4][STEPS][4];
  __shared__ float redl[4][NACC];

  // ---- bulk issue: 2 pred + 10 teacher float4 loads, all in flight at once
  float4 pv0 = *reinterpret_cast<const float4*>(pb + (size_t)y0 * W_ + x0);
  float4 pv1 = *reinterpret_cast<const float4*>(pb + (size_t)(y0 + 1) * W_ + x0);
  float4 row[STEPS];
#pragma unroll
  for (int s = 0; s < STEPS; ++s) {
    const int t    = y0 + s - 3;
    const int trow = t < 0 ? 0 : (t >= H_ ? H_ - 1 : t);   // y-clamp (exact)
    row[s] = *reinterpret_cast<const float4*>(tb + (size_t)trow * W_ + x0);
  }
  // publish wave-edge columns (compiler inserts progressive vmcnt waits)
#pragma unroll
  for (int s = 0; s < STEPS; ++s) {
    if (lane == 0)  { eL[wv][s][0] = row[s].x; eL[wv][s][1] = row[s].y;
                      eL[wv][s][2] = row[s].z; eL[wv][s][3] = row[s].w; }
    if (lane == 63) { eR[wv][s][0] = row[s].x; eR[wv][s][1] = row[s].y;
                      eR[wv][s][2] = row[s].z; eR[wv][s][3] = row[s].w; }
  }
  __syncthreads();

  float acc[NACC];
#pragma unroll
  for (int j = 0; j < NACC; j++) acc[j] = 0.f;

  // full-width rows: ring[s][i], col = x0-3+i (own = i 3..6)
  float ring[STEPS][10];
  float4 pv2, pv3;

#pragma unroll
  for (int s = 0; s < STEPS; ++s) {
    // ---- resolve row s to full width (register shuffles + LDS edges)
    {
      const float a3 = row[s].x, a4 = row[s].y, a5 = row[s].z, a6 = row[s].w;
      ring[s][3] = a3; ring[s][4] = a4; ring[s][5] = a5; ring[s][6] = a6;
      ring[s][0] = __shfl_up(a4, 1, 64);
      ring[s][1] = __shfl_up(a5, 1, 64);
      ring[s][2] = __shfl_up(a6, 1, 64);
      ring[s][7] = __shfl_down(a3, 1, 64);
      ring[s][8] = __shfl_down(a4, 1, 64);
      ring[s][9] = __shfl_down(a5, 1, 64);
      if (lane == 0) {
        if (wv > 0) { ring[s][0] = eR[wv - 1][s][1]; ring[s][1] = eR[wv - 1][s][2];
                      ring[s][2] = eR[wv - 1][s][3]; }
        else        { ring[s][0] = ring[s][1] = ring[s][2] = a3; }   // image left clamp
      }
      if (lane == 63) {
        if (wv < 3) { ring[s][7] = eL[wv + 1][s][0]; ring[s][8] = eL[wv + 1][s][1];
                      ring[s][9] = eL[wv + 1][s][2]; }
        else        { ring[s][7] = ring[s][8] = ring[s][9] = a6; }   // image right clamp
      }
    }
    // staggered pred loads (2-step distance to use at s=8,9)
    if (s == 4) pv2 = *reinterpret_cast<const float4*>(pb + (size_t)(y0 + 2) * W_ + x0);
    if (s == 5) pv3 = *reinterpret_cast<const float4*>(pb + (size_t)(y0 + 3) * W_ + x0);

    // ---- emit output row y = y0+s-6 (teacher rows y+d -> ring[s-6+d+3] = ring[s+d-3])
    if (s >= 6) {
      const float (&rm3)[10] = ring[s - 6];   // own cols only (dy=-3 width 0)
      const float (&rm2)[10] = ring[s - 5];
      const float (&rm1)[10] = ring[s - 4];
      const float (&rc )[10] = ring[s - 3];
      const float (&rp1)[10] = ring[s - 2];
      const float (&rp2)[10] = ring[s - 1];
      const float (&rp3)[10] = ring[s];       // own cols only (dy=+3 width 0)
      const float4 pvv = (s == 6) ? pv0 : (s == 7) ? pv1 : (s == 8) ? pv2 : pv3;
      const float p[TW] = {pvv.x, pvv.y, pvv.z, pvv.w};

      // ===== MAX (dilation) phase =====
      {
        float V3[10], V5[10];
#pragma unroll
        for (int i = 1; i <= 8; ++i) {
          V3[i] = fmaxf(fmaxf(rm1[i], rc[i]), rp1[i]);          // v_max3
          V5[i] = fmaxf(fmaxf(V3[i], rm2[i]), rp2[i]);
        }
#pragma unroll
        for (int c = 0; c < TW; ++c) {
          const int i = c + 3;
          const float V7 = fmaxf(fmaxf(V5[i], rm3[i]), rp3[i]);
          const float d3 = fmaxf(fmaxf(V3[i], rc[i - 1]), rc[i + 1]);
          float d5 = fmaxf(fmaxf(V5[i], V3[i - 1]), V3[i + 1]);
          d5 = fmaxf(fmaxf(d5, rc[i - 2]), rc[i + 2]);
          float d7 = fmaxf(fmaxf(V7, V5[i - 1]), V5[i + 1]);
          d7 = fmaxf(fmaxf(d7, V5[i - 2]), V5[i + 2]);
          d7 = fmaxf(fmaxf(d7, rc[i - 3]), rc[i + 3]);
          acc[0]  += p[c];
          acc[1]  += d3;  acc[2]  = fmaf(p[c], d3, acc[2]);
          acc[5]  += d5;  acc[6]  = fmaf(p[c], d5, acc[6]);
          acc[9]  += d7;  acc[10] = fmaf(p[c], d7, acc[10]);
        }
      }
      // ===== MIN (erosion) phase =====
      {
        float V3[10], V5[10];
#pragma unroll
        for (int i = 1; i <= 8; ++i) {
          V3[i] = fminf(fminf(rm1[i], rc[i]), rp1[i]);          // v_min3
          V5[i] = fminf(fminf(V3[i], rm2[i]), rp2[i]);
        }
#pragma unroll
        for (int c = 0; c < TW; ++c) {
          const int i = c + 3;
          const float V7 = fminf(fminf(V5[i], rm3[i]), rp3[i]);
          const float e3 = fminf(fminf(V3[i], rc[i - 1]), rc[i + 1]);
          float e5 = fminf(fminf(V5[i], V3[i - 1]), V3[i + 1]);
          e5 = fminf(fminf(e5, rc[i - 2]), rc[i + 2]);
          float e7 = fminf(fminf(V7, V5[i - 1]), V5[i + 1]);
          e7 = fminf(fminf(e7, V5[i - 2]), V5[i + 2]);
          e7 = fminf(fminf(e7, rc[i - 3]), rc[i + 3]);
          acc[3]  += e3;  acc[4]  = fmaf(p[c], e3, acc[4]);
          acc[7]  += e5;  acc[8]  = fmaf(p[c], e5, acc[8]);
          acc[11] += e7;  acc[12] = fmaf(p[c], e7, acc[12]);
        }
      }
    }
  }

  // wave (64-lane) shuffle reduction, then cross-wave via LDS
#pragma unroll
  for (int j = 0; j < NACC; j++) {
    float v = acc[j];
#pragma unroll
    for (int off = 32; off > 0; off >>= 1) v += __shfl_down(v, off, 64);
    acc[j] = v;
  }
  if (lane == 0) {
#pragma unroll
    for (int j = 0; j < NACC; j++) redl[wv][j] = acc[j];
  }
  __syncthreads();
  if (tid == 0) {
#pragma unroll
    for (int j = 0; j < NACC; j++)
      partials[j * NBLK + n] = redl[0][j] + redl[1][j] + redl[2][j] + redl[3][j];
  }
}

// Stage-1 reduction: block j sums partials[j*NBLK .. +NBLK) -> red13[j].
__global__ __launch_bounds__(256) void k_red(const float* __restrict__ partials,
                                             float* __restrict__ red13) {
  const int j   = blockIdx.x;
  const int tid = threadIdx.x;
  double a = 0.0;
#pragma unroll
  for (int k = 0; k < NBLK / 256; k++)
    a += (double)partials[j * NBLK + tid + k * 256];   // coalesced, independent
#pragma unroll
  for (int off = 32; off > 0; off >>= 1) a += __shfl_down(a, off, 64);
  __shared__ double red[4];
  const int lane = tid & 63, wv = tid >> 6;
  if (lane == 0) red[wv] = a;
  __syncthreads();
  if (tid == 0) red13[j] = (float)(red[0] + red[1] + red[2] + red[3]);
}

__global__ void k_final(const float* __restrict__ red13, float* __restrict__ out) {
  if (threadIdx.x == 0) {
    double t_[NACC];
#pragma unroll
    for (int j = 0; j < NACC; j++) t_[j] = (double)red13[j];
    const double Sp = t_[0];
    double total = 0.0;
#pragma unroll
    for (int k = 0; k < 3; k++) {
      const double Sd = t_[1 + 4 * k], Id = t_[2 + 4 * k];
      const double Se = t_[3 + 4 * k], Ie = t_[4 + 4 * k];
      double cd = Sp + Sd; if (cd < 1e-7) cd = 1e-7;
      double ce = Sp + Se; if (ce < 1e-7) ce = 1e-7;
      total += (1.0 - 2.0 * Id / cd) * (Sd > 0.0 ? 1.0 : 0.0);
      total += (1.0 - 2.0 * Ie / ce) * (Se > 0.0 ? 1.0 : 0.0);
    }
    out[0] = (float)(total / 3.0);
  }
}

extern "C" void kernel_launch(void* const* d_in, const int* in_sizes, int n_in,
                              void* d_out, int out_size, void* d_ws, size_t ws_size,
                              hipStream_t stream) {
  const float* pred = (const float*)d_in[0];  // pred_student_prob
  const float* tch  = (const float*)d_in[1];  // teacher_prob
  float* partials = (float*)d_ws;                       // NACC*NBLK floats
  float* red13    = (float*)d_ws + NACC * NBLK;         // NACC floats

  k_partials<<<dim3(GX, B_), BT, 0, stream>>>(pred, tch, partials);
  k_red<<<NACC, 256, 0, stream>>>(partials, red13);
  k_final<<<1, 64, 0, stream>>>(red13, (float*)d_out);
}